// Round 1
// baseline (5296.342 us; speedup 1.0000x reference)
//
#include <hip/hip_runtime.h>

#define B_ 64
#define T_ 1024
#define I_ 16
#define H_ 512
#define O_ 3
#define NIN_ 103
#define NEX_ 409

// ---------------------------------------------------------------------------
// One-time 512x512 transpose of W_h2h into workspace (WT[k][j] = W[j][k]) so
// the recurrent inner loop reads coalesced float4 rows of W^T.
// ---------------------------------------------------------------------------
__global__ __launch_bounds__(256) void transpose_w(const float* __restrict__ W,
                                                   float* __restrict__ WT) {
  __shared__ float tile[32][33];
  const int bx = (blockIdx.x & 15) * 32;  // col block in W
  const int by = (blockIdx.x >> 4) * 32;  // row block in W
  const int tx = threadIdx.x & 31;
  const int ty = threadIdx.x >> 5;  // 0..7
#pragma unroll
  for (int r = 0; r < 32; r += 8)
    tile[ty + r][tx] = W[(by + ty + r) * H_ + bx + tx];
  __syncthreads();
#pragma unroll
  for (int r = 0; r < 32; r += 8)
    WT[(bx + ty + r) * H_ + by + tx] = tile[tx][ty + r];
}

// ---------------------------------------------------------------------------
// Persistent per-batch RNN kernel. 1 workgroup = 1 batch sequence (no grid
// sync needed; batches are independent). 1024 threads = 8 K-slices x 128
// j-quads. Sparse outer-product recurrence: only ReLU-active h[k] columns are
// streamed (exact in fp32: skipped terms are exactly 0*w).
// ---------------------------------------------------------------------------
template <bool TRANS>
__global__ __launch_bounds__(1024, 1) void rnn_kernel(
    const float* __restrict__ x, const float* __restrict__ noise,
    const float* __restrict__ W_i2h, const float* __restrict__ b_i2h,
    const float* __restrict__ Wh, const float* __restrict__ WT,
    const float* __restrict__ b_h2h, const float* __restrict__ W_h2o,
    const float* __restrict__ b_h2o, const int* __restrict__ taup,
    const int* __restrict__ dtp, float* __restrict__ out_net,
    float* __restrict__ out_rnn) {
  // compacted active list: pair.x = h value, pair.y = bitcast(column index)
  __shared__ float2 pair_s[544];
  __shared__ float cb_s[H_];        // b_i2h + b_h2h
  __shared__ float w3_s[3 * 416];   // W_h2o rows, padded
  __shared__ float wpart_s[8][3];   // per-wave h2o partials
  __shared__ int wcnt_s[8];         // per-wave active counts
  __shared__ float x_s[I_];
  __shared__ int cntp_s;
  __align__(16) __shared__ float partial_s[8 * H_];  // per-slice partial accs

  const int tid = threadIdx.x;
  const int b = blockIdx.x;
  const int lane = tid & 63;
  const int wave = tid >> 6;
  const int slice = tid >> 7;  // 0..7 (K-slice)
  const int jq = tid & 127;    // j-quad
  const int j4 = jq * 4;

  const float alpha = (float)((double)dtp[0] / (double)taup[0]);
  const float nzscale = (float)(sqrt(2.0 * (double)alpha) * 0.01);

  // ---- one-time setup ----
  float wi[I_];  // W_i2h row for my neuron, register-resident
  if (tid < H_) {
#pragma unroll
    for (int i = 0; i < I_; ++i) wi[i] = W_i2h[tid * I_ + i];
    cb_s[tid] = b_i2h[tid] + b_h2h[tid];
  }
  for (int idx = tid; idx < O_ * NEX_; idx += 1024) {
    int o = idx / NEX_, e = idx - o * NEX_;
    w3_s[o * 416 + e] = W_h2o[idx];
  }
  const float myb = (tid < O_) ? b_h2o[tid] : 0.f;
  if (tid == 0) cntp_s = 0;

  float* rnn_b = out_rnn + (size_t)b * (T_ + 1) * H_;
  float* net_b = out_net + (size_t)b * (T_ + 1) * O_;
  const float* xrow = x + (size_t)b * T_ * I_;
  const float* nrow = noise + (size_t)b * T_ * H_;

  // t = 0 outputs are zeros (h0 = 0)
  if (tid < H_) rnn_b[tid] = 0.f;
  if (tid < O_) net_b[tid] = 0.f;
  __syncthreads();

  int cntp = 0;  // padded active count (multiple of 32), 0 at t=0
  for (int t = 0; t < T_; ++t) {
    // ---- prefetch this step's noise row + x row (consumed after barrier A)
    float nzv = 0.f, xv = 0.f;
    if (tid < H_) nzv = nrow[(size_t)t * H_ + tid];
    if (tid < I_) xv = xrow[t * I_ + tid];

    // ---- sparse outer-product accumulation over active columns ----
    float4 acc = {0.f, 0.f, 0.f, 0.f};
    const int iters = cntp >> 3;  // per-slice trips; multiple of 4
    for (int r = 0; r < iters; r += 4) {
      float hh[4];
      int kk[4];
#pragma unroll
      for (int u = 0; u < 4; ++u) {
        const int m = (r + u) * 8 + slice;
        const float2 p = pair_s[m];
        hh[u] = p.x;
        kk[u] = __float_as_int(p.y);
      }
#pragma unroll
      for (int u = 0; u < 4; ++u) {
        float4 wv;
        if (TRANS) {
          wv = *reinterpret_cast<const float4*>(WT + (size_t)kk[u] * H_ + j4);
        } else {  // fallback: read W_h2h directly (strided, slow but correct)
          wv.x = Wh[(size_t)(j4 + 0) * H_ + kk[u]];
          wv.y = Wh[(size_t)(j4 + 1) * H_ + kk[u]];
          wv.z = Wh[(size_t)(j4 + 2) * H_ + kk[u]];
          wv.w = Wh[(size_t)(j4 + 3) * H_ + kk[u]];
        }
        acc.x += hh[u] * wv.x;
        acc.y += hh[u] * wv.y;
        acc.z += hh[u] * wv.z;
        acc.w += hh[u] * wv.w;
      }
    }
    if (tid < I_) x_s[tid] = xv;
    *reinterpret_cast<float4*>(partial_s + slice * H_ + j4) = acc;
    __syncthreads();  // A

    // ---- epilogue: combine slices, nonlinearity, outputs (waves 0..7) ----
    unsigned long long mask = 0ull;
    float h = 0.f;
    if (tid < H_) {
      float sum = 0.f;
#pragma unroll
      for (int s2 = 0; s2 < 8; ++s2) sum += partial_s[s2 * H_ + tid];
      float xi = 0.f;
#pragma unroll
      for (int i = 0; i < I_; ++i) xi += wi[i] * x_s[i];
      const float pre = alpha * (sum + xi + cb_s[tid]) + nzscale * nzv;
      h = fmaxf(pre, 0.f);
      rnn_b[(size_t)(t + 1) * H_ + tid] = h;

      // h2o projection partials (only excitatory units contribute)
      float p0 = 0.f, p1 = 0.f, p2 = 0.f;
      if (tid >= NIN_) {
        const int e = tid - NIN_;
        p0 = h * w3_s[0 * 416 + e];
        p1 = h * w3_s[1 * 416 + e];
        p2 = h * w3_s[2 * 416 + e];
      }
#pragma unroll
      for (int off = 32; off >= 1; off >>= 1) {
        p0 += __shfl_xor(p0, off, 64);
        p1 += __shfl_xor(p1, off, 64);
        p2 += __shfl_xor(p2, off, 64);
      }
      mask = __ballot(h > 0.f);
      if (lane == 0) {
        wcnt_s[wave] = (int)__popcll(mask);
        wpart_s[wave][0] = p0;
        wpart_s[wave][1] = p1;
        wpart_s[wave][2] = p2;
      }
    }
    __syncthreads();  // B

    // ---- rebuild compacted active list for next step ----
    if (tid < H_) {
      int base = 0, cnt = 0;
#pragma unroll
      for (int w = 0; w < 8; ++w) {
        const int c = wcnt_s[w];
        if (w < wave) base += c;
        cnt += c;
      }
      if (h > 0.f) {
        const int pos = base + (int)__popcll(mask & ((1ull << lane) - 1ull));
        pair_s[pos] = make_float2(h, __int_as_float(tid));
      }
      const int cp = (cnt + 31) & ~31;  // pad to multiple of 32 (unroll 4 x 8)
      if (tid < cp - cnt) pair_s[cnt + tid] = make_float2(0.f, __int_as_float(0));
      if (tid == 0) cntp_s = cp;
      if (tid < O_) {
        float o = myb;
#pragma unroll
        for (int w = 0; w < 8; ++w) o += wpart_s[w][tid];
        net_b[(size_t)(t + 1) * O_ + tid] = o;
      }
    }
    __syncthreads();  // C
    cntp = cntp_s;
  }
}

extern "C" void kernel_launch(void* const* d_in, const int* in_sizes, int n_in,
                              void* d_out, int out_size, void* d_ws,
                              size_t ws_size, hipStream_t stream) {
  const float* x = (const float*)d_in[0];
  const float* noise = (const float*)d_in[1];
  const float* W_i2h = (const float*)d_in[2];
  const float* b_i2h = (const float*)d_in[3];
  const float* W_h2h = (const float*)d_in[4];
  const float* b_h2h = (const float*)d_in[5];
  const float* W_h2o = (const float*)d_in[6];
  const float* b_h2o = (const float*)d_in[7];
  const int* tau = (const int*)d_in[8];
  const int* dt = (const int*)d_in[9];

  float* out_net = (float*)d_out;
  float* out_rnn = (float*)d_out + (size_t)B_ * (T_ + 1) * O_;
  float* WT = (float*)d_ws;

  const bool useT = (d_ws != nullptr) &&
                    (ws_size >= (size_t)H_ * H_ * sizeof(float));
  if (useT) {
    hipLaunchKernelGGL(transpose_w, dim3(256), dim3(256), 0, stream, W_h2h, WT);
    hipLaunchKernelGGL((rnn_kernel<true>), dim3(B_), dim3(1024), 0, stream, x,
                       noise, W_i2h, b_i2h, W_h2h, WT, b_h2h, W_h2o, b_h2o, tau,
                       dt, out_net, out_rnn);
  } else {
    hipLaunchKernelGGL((rnn_kernel<false>), dim3(B_), dim3(1024), 0, stream, x,
                       noise, W_i2h, b_i2h, W_h2h, W_h2h, b_h2h, W_h2o, b_h2o,
                       tau, dt, out_net, out_rnn);
  }
}